// Round 15
// baseline (207.025 us; speedup 1.0000x reference)
//
#include <hip/hip_runtime.h>
#include <math.h>

#define BB 8
#define CC 256
#define NN 4096

typedef float f4 __attribute__((ext_vector_type(4)));
typedef short bh8 __attribute__((ext_vector_type(8)));

__device__ __forceinline__ unsigned short f2bf(float f) {
    unsigned u = __builtin_bit_cast(unsigned, f);
    u += 0x7fff + ((u >> 16) & 1);
    return (unsigned short)(u >> 16);
}
__device__ __forceinline__ unsigned packbf(float a, float b) {
    return (unsigned)f2bf(a) | ((unsigned)f2bf(b) << 16);
}

// v_exp_f32 is natively 2^x — scores are pre-scaled by log2(e) in prep_w
__device__ __forceinline__ float exp2_fast(float x) {
    float r;
    asm("v_exp_f32 %0, %1" : "=v"(r) : "v"(x));
    return r;
}

// ---------------------------------------------------------------------------
// Kernel 0: weights -> Whi/Wlo[320][256] (bf16 hi/lo split) + bcat[320] fp32.
// q rows (o<32) pre-scaled by log2(e). (R14, proven)
// ---------------------------------------------------------------------------
__global__ void prep_w_kernel(const float* __restrict__ Wq, const float* __restrict__ bq,
                              const float* __restrict__ Wk, const float* __restrict__ bk,
                              const float* __restrict__ Wv, const float* __restrict__ bv,
                              unsigned short* __restrict__ Whi, unsigned short* __restrict__ Wlo,
                              float* __restrict__ bcat) {
    const float L2E = 1.4426950408889634f;
    int idx = blockIdx.x * 256 + threadIdx.x;
    if (idx < 320) {
        bcat[idx] = (idx < 32) ? bq[idx] * L2E : (idx < 64 ? bk[idx - 32] : bv[idx - 64]);
    }
    if (idx < 320 * 256) {
        int o = idx >> 8;
        int c = idx & 255;
        float v = (o < 32) ? Wq[o * 256 + c] * L2E
                           : (o < 64 ? Wk[(o - 32) * 256 + c] : Wv[(o - 64) * 256 + c]);
        unsigned short hi = f2bf(v);
        float vhi = __builtin_bit_cast(float, ((unsigned)hi) << 16);
        Whi[idx] = hi;
        Wlo[idx] = f2bf(v - vhi);
    }
}

// ---------------------------------------------------------------------------
// Kernel 1: QKV projection via MFMA. (R14, proven)
// ---------------------------------------------------------------------------
__global__ __launch_bounds__(256, 2) void qkv_kernel(
    const float* __restrict__ x, const unsigned short* __restrict__ Whi,
    const unsigned short* __restrict__ Wlo, const float* __restrict__ bcat,
    unsigned short* __restrict__ q64, unsigned short* __restrict__ k64,
    unsigned short* __restrict__ vC) {
    __shared__ __align__(16) char smem[67584];
    unsigned short* xsTh = (unsigned short*)smem;            // [64][264]
    unsigned short* xsTl = (unsigned short*)(smem + 33792);  // [64][264]
    unsigned short* qkl = (unsigned short*)smem;             // [64][128] overlay
    unsigned short* vsl = (unsigned short*)(smem + 16384);   // [256][66] overlay

    int blk = blockIdx.x;
    int b = blk >> 6;
    int i0 = (blk & 63) << 6;
    int t = threadIdx.x;
    const float* xb = x + ((size_t)b << 20);

    for (int idx = t; idx < 256 * 64; idx += 256) {
        int c = idx >> 6, ii = idx & 63;
        float v = xb[((size_t)c << 12) + i0 + ii];
        unsigned short hi = f2bf(v);
        float vhi = __builtin_bit_cast(float, ((unsigned)hi) << 16);
        xsTh[ii * 264 + c] = hi;
        xsTl[ii * 264 + c] = f2bf(v - vhi);
    }
    __syncthreads();

    int lane = t & 63;
    int w = t >> 6;
    int g = lane >> 4;
    int li = lane & 15;

    f4 acc[5][4];
#pragma unroll
    for (int tt = 0; tt < 5; ++tt)
#pragma unroll
        for (int it = 0; it < 4; ++it) acc[tt][it] = (f4){0.f, 0.f, 0.f, 0.f};

#pragma unroll
    for (int tt = 0; tt < 5; ++tt) {
        int ot = w + 4 * tt;
        bool qk = (ot < 4);
        const unsigned short* wrh = Whi + (size_t)(16 * ot + li) * 256 + 8 * g;
        const unsigned short* wrl = Wlo + (size_t)(16 * ot + li) * 256 + 8 * g;
        bh8 ah[8], al[8];
#pragma unroll
        for (int ck = 0; ck < 8; ++ck) {
            ah[ck] = *(const bh8*)(wrh + 32 * ck);
            al[ck] = *(const bh8*)(wrl + 32 * ck);
        }
#pragma unroll
        for (int it = 0; it < 4; ++it) {
            const unsigned short* xrh = xsTh + (16 * it + li) * 264 + 8 * g;
            const unsigned short* xrl = xsTl + (16 * it + li) * 264 + 8 * g;
            f4 a = acc[tt][it];
            if (qk) {
#pragma unroll
                for (int ck = 0; ck < 8; ++ck) {
                    bh8 xh = *(const bh8*)(xrh + 32 * ck);
                    bh8 xl = *(const bh8*)(xrl + 32 * ck);
                    a = __builtin_amdgcn_mfma_f32_16x16x32_bf16(ah[ck], xh, a, 0, 0, 0);
                    a = __builtin_amdgcn_mfma_f32_16x16x32_bf16(al[ck], xh, a, 0, 0, 0);
                    a = __builtin_amdgcn_mfma_f32_16x16x32_bf16(ah[ck], xl, a, 0, 0, 0);
                }
            } else {
#pragma unroll
                for (int ck = 0; ck < 8; ++ck) {
                    bh8 xh = *(const bh8*)(xrh + 32 * ck);
                    a = __builtin_amdgcn_mfma_f32_16x16x32_bf16(ah[ck], xh, a, 0, 0, 0);
                    a = __builtin_amdgcn_mfma_f32_16x16x32_bf16(al[ck], xh, a, 0, 0, 0);
                }
            }
            acc[tt][it] = a;
        }
    }
    __syncthreads();

#pragma unroll
    for (int tt = 0; tt < 5; ++tt) {
        int ot = w + 4 * tt;
        float bias[4];
#pragma unroll
        for (int e = 0; e < 4; ++e) bias[e] = bcat[16 * ot + 4 * g + e];
#pragma unroll
        for (int it = 0; it < 4; ++it) {
            int ii = 16 * it + li;
#pragma unroll
            for (int e = 0; e < 4; ++e) {
                int o = 16 * ot + 4 * g + e;
                float v = acc[tt][it][e] + bias[e];
                if (o < 64) {
                    unsigned short hi = f2bf(v);
                    float vhi = __builtin_bit_cast(float, ((unsigned)hi) << 16);
                    unsigned short lo = f2bf(v - vhi);
                    if (o < 32) {
                        qkl[ii * 128 + o] = hi;
                        qkl[ii * 128 + 32 + o] = lo;
                    } else {
                        qkl[ii * 128 + 32 + o] = hi;
                        qkl[ii * 128 + 64 + o] = lo;
                    }
                } else {
                    vsl[(o - 64) * 66 + ii] = f2bf(v);
                }
            }
        }
    }
    __syncthreads();

    const unsigned* qk32 = (const unsigned*)qkl;
    unsigned* qb = (unsigned*)(q64 + ((size_t)(b * NN + i0)) * 64);
    unsigned* kb = (unsigned*)(k64 + ((size_t)(b * NN + i0)) * 64);
    for (int idx = t; idx < 64 * 32; idx += 256) {
        int row = idx >> 5, dw = idx & 31;
        qb[row * 32 + dw] = qk32[row * 64 + dw];
        kb[row * 32 + dw] = qk32[row * 64 + 32 + dw];
    }
    for (int idx = t; idx < 256 * 32; idx += 256) {
        int c = idx >> 5, dw = idx & 31;
        unsigned val = *(const unsigned*)(vsl + c * 66 + 2 * dw);
        int i = 2 * dw;
        int p = 32 * (i >> 5) + 8 * ((i >> 2) & 3) + 4 * ((i >> 4) & 1) + (i & 3);
        *(unsigned*)(vC + ((size_t)(b * CC + c)) * NN + i0 + p) = val;
    }
}

// ---------------------------------------------------------------------------
// Kernel 2: MFMA flash attention + residual. P RETIMED BY ONE STEP (T15).
// Grid 512, 4 waves x 16 q, 2 blocks/CU. Step t runs PV[t] (P from last step)
// IN PARALLEL with QK[t+1]->softmax[t+1]->pack[t+1] (independent chains; MFMA
// and VALU pipes overlap). Pending rescale sc (from prep[t+1]) applied to acc
// AFTER PV[t] — exact same float sequence per tile as before.
// Vote-only defer-max; per-lane l partial; sigma-permuted V (P = own scores);
// V [256][64] bf16 LDS XOR-swizzled, double-buffered via global_load_lds.
// ---------------------------------------------------------------------------
__global__ __launch_bounds__(256, 2) void attn_kernel(
    const unsigned short* __restrict__ q64, const unsigned short* __restrict__ k64,
    const unsigned short* __restrict__ vC, const float* __restrict__ x,
    const float* __restrict__ gamma, float* __restrict__ out) {
    __shared__ unsigned short vs[2][256 * 64];  // 64KB double-buffered V

    int t = threadIdx.x;
    int lane = t & 63;
    int w = t >> 6;
    int g = lane >> 4;
    int li = lane & 15;
    int blk = blockIdx.x;
    int b = blk & 7;            // XCD-affine batch mapping
    int i0 = (blk >> 3) << 6;   // 64-query tile
    int qb = i0 + 16 * w;       // wave's query base (16 queries)

    const unsigned short* vb = vC + ((size_t)b * CC) * NN;
    const unsigned short* kb = k64 + ((size_t)b * NN) * 64;

    bh8 qf[2];
#pragma unroll
    for (int s = 0; s < 2; ++s)
        qf[s] = *(const bh8*)(q64 + ((size_t)(b * NN + qb + li)) * 64 + s * 32 + 8 * g);

    const unsigned short* vsrcb[8];
#pragma unroll
    for (int s = 0; s < 8; ++s) {
        int c = 64 * w + 8 * s + (lane >> 3);
        int slot = (lane & 7) ^ (c & 7);
        vsrcb[s] = vb + (size_t)c * NN + slot * 8;
    }
    const unsigned short* ksrcb[8];
#pragma unroll
    for (int jt = 0; jt < 4; ++jt)
#pragma unroll
        for (int s = 0; s < 2; ++s)
            ksrcb[jt * 2 + s] = kb + (size_t)(16 * jt + li) * 64 + s * 32 + 8 * g;

    f4 acc[16];
#pragma unroll
    for (int ct = 0; ct < 16; ++ct) acc[ct] = (f4){0.f, 0.f, 0.f, 0.f};
    float m, l;

    auto stageV = [&](int buf, int j0) {
#pragma unroll
        for (int s = 0; s < 8; ++s) {
            __builtin_amdgcn_global_load_lds(
                (const __attribute__((address_space(1))) unsigned int*)(vsrcb[s] + j0),
                (__attribute__((address_space(3))) unsigned int*)(&vs[buf][(64 * w + 8 * s) * 64]),
                16, 0, 0);
        }
    };
    auto loadK = [&](bh8 (&kf)[4][2], int j0) {
        size_t joff = (size_t)j0 * 64;
#pragma unroll
        for (int jt = 0; jt < 4; ++jt)
#pragma unroll
            for (int s = 0; s < 2; ++s)
                kf[jt][s] = *(const bh8*)(ksrcb[jt * 2 + s] + joff);
    };
    auto qkComp = [&](f4 (&sOut)[4], bh8 (&kc)[4][2]) {
#pragma unroll
        for (int jt = 0; jt < 4; ++jt) {
            f4 a = {0.f, 0.f, 0.f, 0.f};
            a = __builtin_amdgcn_mfma_f32_16x16x32_bf16(kc[jt][0], qf[0], a, 0, 0, 0);
            a = __builtin_amdgcn_mfma_f32_16x16x32_bf16(kc[jt][1], qf[0], a, 0, 0, 0);
            a = __builtin_amdgcn_mfma_f32_16x16x32_bf16(kc[jt][0], qf[1], a, 0, 0, 0);
            sOut[jt] = a;
        }
    };
    auto packP = [&](f4 (&sT)[4], bh8 (&pN)[2]) {
        union { unsigned u[4]; bh8 v; } pf0, pf1;
        pf0.u[0] = packbf(sT[0][0], sT[0][1]);
        pf0.u[1] = packbf(sT[0][2], sT[0][3]);
        pf0.u[2] = packbf(sT[1][0], sT[1][1]);
        pf0.u[3] = packbf(sT[1][2], sT[1][3]);
        pf1.u[0] = packbf(sT[2][0], sT[2][1]);
        pf1.u[1] = packbf(sT[2][2], sT[2][3]);
        pf1.u[2] = packbf(sT[3][0], sT[3][1]);
        pf1.u[3] = packbf(sT[3][2], sT[3][3]);
        pN[0] = pf0.v;
        pN[1] = pf1.v;
    };

    bh8 kf0[4][2], kf1[4][2];
    bh8 P0[2], P1[2];

    // prologue: V[0] staged, K[0]/K[1] in regs; softmax[0] done eagerly
    stageV(0, 0);
    loadK(kf0, 0);
    loadK(kf1, 64);
    {
        f4 sT[4];
        qkComp(sT, kf0);
        float mx = sT[0][0];
#pragma unroll
        for (int jt = 0; jt < 4; ++jt)
#pragma unroll
            for (int e = 0; e < 4; ++e) mx = fmaxf(mx, sT[jt][e]);
        mx = fmaxf(mx, __shfl_xor(mx, 16));
        mx = fmaxf(mx, __shfl_xor(mx, 32));
        m = mx;
        float sum = 0.f;
#pragma unroll
        for (int jt = 0; jt < 4; ++jt)
#pragma unroll
            for (int e = 0; e < 4; ++e) {
                float p = exp2_fast(sT[jt][e] - m);
                sT[jt][e] = p;
                sum += p;
            }
        l = sum;
        packP(sT, P0);
    }
    __syncthreads();

    // step t: PV[t] with pC (prepared last step) ∥ prep[t+1] into pN.
    auto step = [&](int tt, bh8 (&kNext)[4][2], bh8 (&kLoad)[4][2],
                    bh8 (&pC)[2], bh8 (&pN)[2], int buf) {
        if (tt < 63) stageV(buf ^ 1, (tt + 1) << 6);
        if (tt < 62) loadK(kLoad, (tt + 2) << 6);

        // ---- prepare tile tt+1 (independent of PV[tt] below) ----
        bool resc = false;
        float sc = 1.f;
        if (tt < 63) {
            f4 sT[4];
            qkComp(sT, kNext);
            float mx = sT[0][0];
#pragma unroll
            for (int jt = 0; jt < 4; ++jt)
#pragma unroll
                for (int e = 0; e < 4; ++e) mx = fmaxf(mx, sT[jt][e]);
            if (!__all(mx <= m + 11.541561f)) {
                mx = fmaxf(mx, __shfl_xor(mx, 16));
                mx = fmaxf(mx, __shfl_xor(mx, 32));
                float mnew = fmaxf(m, mx);
                sc = exp2_fast(m - mnew);
                l *= sc;
                m = mnew;
                resc = true;
            }
            float sum = 0.f;
#pragma unroll
            for (int jt = 0; jt < 4; ++jt)
#pragma unroll
                for (int e = 0; e < 4; ++e) {
                    float p = exp2_fast(sT[jt][e] - m);
                    sT[jt][e] = p;
                    sum += p;
                }
            l += sum;
            packP(sT, pN);
        }

        // ---- PV[tt] with pC (no dependence on the prep above) ----
        const char* vsb = (const char*)vs[buf];
        __builtin_amdgcn_s_setprio(1);
#pragma unroll
        for (int h = 0; h < 2; ++h) {
#pragma unroll
            for (int ct = 0; ct < 16; ++ct) {
                int c = 16 * ct + li;
                int off = c * 128 + ((64 * h + 16 * g) ^ ((c & 7) << 4));
                bh8 vf = *(const bh8*)(vsb + off);
                acc[ct] = __builtin_amdgcn_mfma_f32_16x16x32_bf16(vf, pC[h], acc[ct], 0, 0, 0);
            }
        }
        __builtin_amdgcn_s_setprio(0);

        // ---- deferred rescale (commutes exactly: acc basis m_t -> m_{t+1})
        if (resc) {
#pragma unroll
            for (int ct = 0; ct < 16; ++ct)
#pragma unroll
                for (int e = 0; e < 4; ++e) acc[ct][e] *= sc;
        }
        __syncthreads();  // V[tt+1] staged (vmcnt drained), vs[buf] reads done
    };

    for (int tt = 0; tt < 64; tt += 2) {
        step(tt, kf1, kf0, P0, P1, 0);
        step(tt + 1, kf0, kf1, P1, P0, 1);
    }

    // ---- reduce l across the 4-lane query group (deferred) ----
    l += __shfl_xor(l, 16);
    l += __shfl_xor(l, 32);

    // ---- epilogue: out = gamma*(acc/l) + x ----
    float gm = gamma[0];
    float rl = 1.f / l;
    const float* xb = x + ((size_t)b * CC) * NN;
    float* ob = out + ((size_t)b * CC) * NN;
    int i = qb + li;
#pragma unroll
    for (int ct = 0; ct < 16; ++ct)
#pragma unroll
        for (int e = 0; e < 4; ++e) {
            int c = 16 * ct + 4 * g + e;
            size_t idx = (size_t)c * NN + i;
            ob[idx] = gm * (acc[ct][e] * rl) + xb[idx];
        }
}

// ---------------------------------------------------------------------------
extern "C" void kernel_launch(void* const* d_in, const int* in_sizes, int n_in,
                              void* d_out, int out_size, void* d_ws, size_t ws_size,
                              hipStream_t stream) {
    const float* x = (const float*)d_in[0];
    const float* Wq = (const float*)d_in[1];
    const float* bq = (const float*)d_in[2];
    const float* Wk = (const float*)d_in[3];
    const float* bk = (const float*)d_in[4];
    const float* Wv = (const float*)d_in[5];
    const float* bv = (const float*)d_in[6];
    const float* gamma = (const float*)d_in[7];
    float* out = (float*)d_out;

    // workspace layout (bytes):
    // q64 @0 (4MB) | k64 @4MB | vC @8MB (16MB) | Whi @24MB (160KB) |
    // Wlo @24MB+160KB | bcat @24MB+320KB
    unsigned short* ws16 = (unsigned short*)d_ws;
    unsigned short* q64w = ws16;
    unsigned short* k64w = ws16 + 2097152;
    unsigned short* vCw = ws16 + 4194304;
    unsigned short* Whiw = ws16 + 12582912;
    unsigned short* Wlow = Whiw + 81920;
    float* bcatw = (float*)(Wlow + 81920);

    prep_w_kernel<<<320, 256, 0, stream>>>(Wq, bq, Wk, bk, Wv, bv, Whiw, Wlow, bcatw);
    qkv_kernel<<<BB * (NN / 64), 256, 0, stream>>>(x, Whiw, Wlow, bcatw, q64w, k64w, vCw);
    attn_kernel<<<512, 256, 0, stream>>>(q64w, k64w, vCw, x, gamma, out);
}

// Round 16
// 205.685 us; speedup vs baseline: 1.0065x; 1.0065x over previous
//
#include <hip/hip_runtime.h>
#include <math.h>

#define BB 8
#define CC 256
#define NN 4096

typedef float f4 __attribute__((ext_vector_type(4)));
typedef short bh8 __attribute__((ext_vector_type(8)));

__device__ __forceinline__ unsigned short f2bf(float f) {
    unsigned u = __builtin_bit_cast(unsigned, f);
    u += 0x7fff + ((u >> 16) & 1);
    return (unsigned short)(u >> 16);
}
__device__ __forceinline__ unsigned packbf(float a, float b) {
    return (unsigned)f2bf(a) | ((unsigned)f2bf(b) << 16);
}

// v_exp_f32 is natively 2^x — scores are pre-scaled by log2(e) in prep_w
__device__ __forceinline__ float exp2_fast(float x) {
    float r;
    asm("v_exp_f32 %0, %1" : "=v"(r) : "v"(x));
    return r;
}

// ---------------------------------------------------------------------------
// Kernel 0: weights -> Whi/Wlo[320][256] (bf16 hi/lo split) + bcat[320] fp32.
// q rows (o<32) pre-scaled by log2(e). (R14, proven)
// ---------------------------------------------------------------------------
__global__ void prep_w_kernel(const float* __restrict__ Wq, const float* __restrict__ bq,
                              const float* __restrict__ Wk, const float* __restrict__ bk,
                              const float* __restrict__ Wv, const float* __restrict__ bv,
                              unsigned short* __restrict__ Whi, unsigned short* __restrict__ Wlo,
                              float* __restrict__ bcat) {
    const float L2E = 1.4426950408889634f;
    int idx = blockIdx.x * 256 + threadIdx.x;
    if (idx < 320) {
        bcat[idx] = (idx < 32) ? bq[idx] * L2E : (idx < 64 ? bk[idx - 32] : bv[idx - 64]);
    }
    if (idx < 320 * 256) {
        int o = idx >> 8;
        int c = idx & 255;
        float v = (o < 32) ? Wq[o * 256 + c] * L2E
                           : (o < 64 ? Wk[(o - 32) * 256 + c] : Wv[(o - 64) * 256 + c]);
        unsigned short hi = f2bf(v);
        float vhi = __builtin_bit_cast(float, ((unsigned)hi) << 16);
        Whi[idx] = hi;
        Wlo[idx] = f2bf(v - vhi);
    }
}

// ---------------------------------------------------------------------------
// Kernel 1: QKV projection via MFMA. (R14, proven)
// ---------------------------------------------------------------------------
__global__ __launch_bounds__(256, 2) void qkv_kernel(
    const float* __restrict__ x, const unsigned short* __restrict__ Whi,
    const unsigned short* __restrict__ Wlo, const float* __restrict__ bcat,
    unsigned short* __restrict__ q64, unsigned short* __restrict__ k64,
    unsigned short* __restrict__ vC) {
    __shared__ __align__(16) char smem[67584];
    unsigned short* xsTh = (unsigned short*)smem;            // [64][264]
    unsigned short* xsTl = (unsigned short*)(smem + 33792);  // [64][264]
    unsigned short* qkl = (unsigned short*)smem;             // [64][128] overlay
    unsigned short* vsl = (unsigned short*)(smem + 16384);   // [256][66] overlay

    int blk = blockIdx.x;
    int b = blk >> 6;
    int i0 = (blk & 63) << 6;
    int t = threadIdx.x;
    const float* xb = x + ((size_t)b << 20);

    for (int idx = t; idx < 256 * 64; idx += 256) {
        int c = idx >> 6, ii = idx & 63;
        float v = xb[((size_t)c << 12) + i0 + ii];
        unsigned short hi = f2bf(v);
        float vhi = __builtin_bit_cast(float, ((unsigned)hi) << 16);
        xsTh[ii * 264 + c] = hi;
        xsTl[ii * 264 + c] = f2bf(v - vhi);
    }
    __syncthreads();

    int lane = t & 63;
    int w = t >> 6;
    int g = lane >> 4;
    int li = lane & 15;

    f4 acc[5][4];
#pragma unroll
    for (int tt = 0; tt < 5; ++tt)
#pragma unroll
        for (int it = 0; it < 4; ++it) acc[tt][it] = (f4){0.f, 0.f, 0.f, 0.f};

#pragma unroll
    for (int tt = 0; tt < 5; ++tt) {
        int ot = w + 4 * tt;
        bool qk = (ot < 4);
        const unsigned short* wrh = Whi + (size_t)(16 * ot + li) * 256 + 8 * g;
        const unsigned short* wrl = Wlo + (size_t)(16 * ot + li) * 256 + 8 * g;
        bh8 ah[8], al[8];
#pragma unroll
        for (int ck = 0; ck < 8; ++ck) {
            ah[ck] = *(const bh8*)(wrh + 32 * ck);
            al[ck] = *(const bh8*)(wrl + 32 * ck);
        }
#pragma unroll
        for (int it = 0; it < 4; ++it) {
            const unsigned short* xrh = xsTh + (16 * it + li) * 264 + 8 * g;
            const unsigned short* xrl = xsTl + (16 * it + li) * 264 + 8 * g;
            f4 a = acc[tt][it];
            if (qk) {
#pragma unroll
                for (int ck = 0; ck < 8; ++ck) {
                    bh8 xh = *(const bh8*)(xrh + 32 * ck);
                    bh8 xl = *(const bh8*)(xrl + 32 * ck);
                    a = __builtin_amdgcn_mfma_f32_16x16x32_bf16(ah[ck], xh, a, 0, 0, 0);
                    a = __builtin_amdgcn_mfma_f32_16x16x32_bf16(al[ck], xh, a, 0, 0, 0);
                    a = __builtin_amdgcn_mfma_f32_16x16x32_bf16(ah[ck], xl, a, 0, 0, 0);
                }
            } else {
#pragma unroll
                for (int ck = 0; ck < 8; ++ck) {
                    bh8 xh = *(const bh8*)(xrh + 32 * ck);
                    a = __builtin_amdgcn_mfma_f32_16x16x32_bf16(ah[ck], xh, a, 0, 0, 0);
                    a = __builtin_amdgcn_mfma_f32_16x16x32_bf16(al[ck], xh, a, 0, 0, 0);
                }
            }
            acc[tt][it] = a;
        }
    }
    __syncthreads();

#pragma unroll
    for (int tt = 0; tt < 5; ++tt) {
        int ot = w + 4 * tt;
        float bias[4];
#pragma unroll
        for (int e = 0; e < 4; ++e) bias[e] = bcat[16 * ot + 4 * g + e];
#pragma unroll
        for (int it = 0; it < 4; ++it) {
            int ii = 16 * it + li;
#pragma unroll
            for (int e = 0; e < 4; ++e) {
                int o = 16 * ot + 4 * g + e;
                float v = acc[tt][it][e] + bias[e];
                if (o < 64) {
                    unsigned short hi = f2bf(v);
                    float vhi = __builtin_bit_cast(float, ((unsigned)hi) << 16);
                    unsigned short lo = f2bf(v - vhi);
                    if (o < 32) {
                        qkl[ii * 128 + o] = hi;
                        qkl[ii * 128 + 32 + o] = lo;
                    } else {
                        qkl[ii * 128 + 32 + o] = hi;
                        qkl[ii * 128 + 64 + o] = lo;
                    }
                } else {
                    vsl[(o - 64) * 66 + ii] = f2bf(v);
                }
            }
        }
    }
    __syncthreads();

    const unsigned* qk32 = (const unsigned*)qkl;
    unsigned* qb = (unsigned*)(q64 + ((size_t)(b * NN + i0)) * 64);
    unsigned* kb = (unsigned*)(k64 + ((size_t)(b * NN + i0)) * 64);
    for (int idx = t; idx < 64 * 32; idx += 256) {
        int row = idx >> 5, dw = idx & 31;
        qb[row * 32 + dw] = qk32[row * 64 + dw];
        kb[row * 32 + dw] = qk32[row * 64 + 32 + dw];
    }
    for (int idx = t; idx < 256 * 32; idx += 256) {
        int c = idx >> 5, dw = idx & 31;
        unsigned val = *(const unsigned*)(vsl + c * 66 + 2 * dw);
        int i = 2 * dw;
        int p = 32 * (i >> 5) + 8 * ((i >> 2) & 3) + 4 * ((i >> 4) & 1) + (i & 3);
        *(unsigned*)(vC + ((size_t)(b * CC + c)) * NN + i0 + p) = val;
    }
}

// ---------------------------------------------------------------------------
// Kernel 2: MFMA flash attention + residual. PV-LOCAL BATCHED READ PIPELINE.
// Grid 512, 4 waves x 16 q, 2 blocks/CU. T15 retiming kept (PV[t] uses P
// prepared in step t-1, independent of this step's softmax).
// PV restructured: 4 batches of 8 {ds_read_b128} / 8 {MFMA}, each batch's
// reads issued one batch ahead — LDS latency hides under MFMA issue instead
// of serializing per-iteration. Live ranges confined to the PV phase.
// Identical math/operands/order-of-accumulation to R15. s_setprio removed.
// ---------------------------------------------------------------------------
__global__ __launch_bounds__(256, 2) void attn_kernel(
    const unsigned short* __restrict__ q64, const unsigned short* __restrict__ k64,
    const unsigned short* __restrict__ vC, const float* __restrict__ x,
    const float* __restrict__ gamma, float* __restrict__ out) {
    __shared__ unsigned short vs[2][256 * 64];  // 64KB double-buffered V

    int t = threadIdx.x;
    int lane = t & 63;
    int w = t >> 6;
    int g = lane >> 4;
    int li = lane & 15;
    int blk = blockIdx.x;
    int b = blk & 7;            // XCD-affine batch mapping
    int i0 = (blk >> 3) << 6;   // 64-query tile
    int qb = i0 + 16 * w;       // wave's query base (16 queries)

    const unsigned short* vb = vC + ((size_t)b * CC) * NN;
    const unsigned short* kb = k64 + ((size_t)b * NN) * 64;

    bh8 qf[2];
#pragma unroll
    for (int s = 0; s < 2; ++s)
        qf[s] = *(const bh8*)(q64 + ((size_t)(b * NN + qb + li)) * 64 + s * 32 + 8 * g);

    const unsigned short* vsrcb[8];
#pragma unroll
    for (int s = 0; s < 8; ++s) {
        int c = 64 * w + 8 * s + (lane >> 3);
        int slot = (lane & 7) ^ (c & 7);
        vsrcb[s] = vb + (size_t)c * NN + slot * 8;
    }
    const unsigned short* ksrcb[8];
#pragma unroll
    for (int jt = 0; jt < 4; ++jt)
#pragma unroll
        for (int s = 0; s < 2; ++s)
            ksrcb[jt * 2 + s] = kb + (size_t)(16 * jt + li) * 64 + s * 32 + 8 * g;

    f4 acc[16];
#pragma unroll
    for (int ct = 0; ct < 16; ++ct) acc[ct] = (f4){0.f, 0.f, 0.f, 0.f};
    float m, l;

    auto stageV = [&](int buf, int j0) {
#pragma unroll
        for (int s = 0; s < 8; ++s) {
            __builtin_amdgcn_global_load_lds(
                (const __attribute__((address_space(1))) unsigned int*)(vsrcb[s] + j0),
                (__attribute__((address_space(3))) unsigned int*)(&vs[buf][(64 * w + 8 * s) * 64]),
                16, 0, 0);
        }
    };
    auto loadK = [&](bh8 (&kf)[4][2], int j0) {
        size_t joff = (size_t)j0 * 64;
#pragma unroll
        for (int jt = 0; jt < 4; ++jt)
#pragma unroll
            for (int s = 0; s < 2; ++s)
                kf[jt][s] = *(const bh8*)(ksrcb[jt * 2 + s] + joff);
    };
    auto qkComp = [&](f4 (&sOut)[4], bh8 (&kc)[4][2]) {
#pragma unroll
        for (int jt = 0; jt < 4; ++jt) {
            f4 a = {0.f, 0.f, 0.f, 0.f};
            a = __builtin_amdgcn_mfma_f32_16x16x32_bf16(kc[jt][0], qf[0], a, 0, 0, 0);
            a = __builtin_amdgcn_mfma_f32_16x16x32_bf16(kc[jt][1], qf[0], a, 0, 0, 0);
            a = __builtin_amdgcn_mfma_f32_16x16x32_bf16(kc[jt][0], qf[1], a, 0, 0, 0);
            sOut[jt] = a;
        }
    };
    auto packP = [&](f4 (&sT)[4], bh8 (&pN)[2]) {
        union { unsigned u[4]; bh8 v; } pf0, pf1;
        pf0.u[0] = packbf(sT[0][0], sT[0][1]);
        pf0.u[1] = packbf(sT[0][2], sT[0][3]);
        pf0.u[2] = packbf(sT[1][0], sT[1][1]);
        pf0.u[3] = packbf(sT[1][2], sT[1][3]);
        pf1.u[0] = packbf(sT[2][0], sT[2][1]);
        pf1.u[1] = packbf(sT[2][2], sT[2][3]);
        pf1.u[2] = packbf(sT[3][0], sT[3][1]);
        pf1.u[3] = packbf(sT[3][2], sT[3][3]);
        pN[0] = pf0.v;
        pN[1] = pf1.v;
    };

    bh8 kf0[4][2], kf1[4][2];
    bh8 P0[2], P1[2];

    // prologue: V[0] staged, K[0]/K[1] in regs; softmax[0] done eagerly
    stageV(0, 0);
    loadK(kf0, 0);
    loadK(kf1, 64);
    {
        f4 sT[4];
        qkComp(sT, kf0);
        float mx = sT[0][0];
#pragma unroll
        for (int jt = 0; jt < 4; ++jt)
#pragma unroll
            for (int e = 0; e < 4; ++e) mx = fmaxf(mx, sT[jt][e]);
        mx = fmaxf(mx, __shfl_xor(mx, 16));
        mx = fmaxf(mx, __shfl_xor(mx, 32));
        m = mx;
        float sum = 0.f;
#pragma unroll
        for (int jt = 0; jt < 4; ++jt)
#pragma unroll
            for (int e = 0; e < 4; ++e) {
                float p = exp2_fast(sT[jt][e] - m);
                sT[jt][e] = p;
                sum += p;
            }
        l = sum;
        packP(sT, P0);
    }
    __syncthreads();

    // step t: PV[t] with pC (prepared last step) ∥ prep[t+1] into pN.
    auto step = [&](int tt, bh8 (&kNext)[4][2], bh8 (&kLoad)[4][2],
                    bh8 (&pC)[2], bh8 (&pN)[2], int buf) {
        if (tt < 63) stageV(buf ^ 1, (tt + 1) << 6);
        if (tt < 62) loadK(kLoad, (tt + 2) << 6);

        // ---- prepare tile tt+1 (independent of PV[tt] below) ----
        bool resc = false;
        float sc = 1.f;
        if (tt < 63) {
            f4 sT[4];
            qkComp(sT, kNext);
            float mx = sT[0][0];
#pragma unroll
            for (int jt = 0; jt < 4; ++jt)
#pragma unroll
                for (int e = 0; e < 4; ++e) mx = fmaxf(mx, sT[jt][e]);
            if (!__all(mx <= m + 11.541561f)) {
                mx = fmaxf(mx, __shfl_xor(mx, 16));
                mx = fmaxf(mx, __shfl_xor(mx, 32));
                float mnew = fmaxf(m, mx);
                sc = exp2_fast(m - mnew);
                l *= sc;
                m = mnew;
                resc = true;
            }
            float sum = 0.f;
#pragma unroll
            for (int jt = 0; jt < 4; ++jt)
#pragma unroll
                for (int e = 0; e < 4; ++e) {
                    float p = exp2_fast(sT[jt][e] - m);
                    sT[jt][e] = p;
                    sum += p;
                }
            l += sum;
            packP(sT, pN);
        }

        // ---- PV[tt] with pC: 4-batch software-pipelined ds_reads ----
        const char* vsb = (const char*)vs[buf];
        auto vld = [&](int ct, int h) -> bh8 {
            int off = (16 * ct + li) * 128 + ((64 * h + 16 * g) ^ ((li & 7) << 4));
            return *(const bh8*)(vsb + off);
        };
        bh8 va[8], vb2[8];
#pragma unroll
        for (int ct = 0; ct < 8; ++ct) va[ct] = vld(ct, 0);          // B0 reads
#pragma unroll
        for (int ct = 0; ct < 8; ++ct) vb2[ct] = vld(ct + 8, 0);     // B1 reads
#pragma unroll
        for (int ct = 0; ct < 8; ++ct)                               // B0 MFMAs
            acc[ct] = __builtin_amdgcn_mfma_f32_16x16x32_bf16(va[ct], pC[0], acc[ct], 0, 0, 0);
#pragma unroll
        for (int ct = 0; ct < 8; ++ct) va[ct] = vld(ct, 1);          // B2 reads
#pragma unroll
        for (int ct = 0; ct < 8; ++ct)                               // B1 MFMAs
            acc[ct + 8] = __builtin_amdgcn_mfma_f32_16x16x32_bf16(vb2[ct], pC[0], acc[ct + 8], 0, 0, 0);
#pragma unroll
        for (int ct = 0; ct < 8; ++ct) vb2[ct] = vld(ct + 8, 1);     // B3 reads
#pragma unroll
        for (int ct = 0; ct < 8; ++ct)                               // B2 MFMAs
            acc[ct] = __builtin_amdgcn_mfma_f32_16x16x32_bf16(va[ct], pC[1], acc[ct], 0, 0, 0);
#pragma unroll
        for (int ct = 0; ct < 8; ++ct)                               // B3 MFMAs
            acc[ct + 8] = __builtin_amdgcn_mfma_f32_16x16x32_bf16(vb2[ct], pC[1], acc[ct + 8], 0, 0, 0);

        // ---- deferred rescale (commutes exactly: acc basis m_t -> m_{t+1})
        if (resc) {
#pragma unroll
            for (int ct = 0; ct < 16; ++ct)
#pragma unroll
                for (int e = 0; e < 4; ++e) acc[ct][e] *= sc;
        }
        __syncthreads();  // V[tt+1] staged (vmcnt drained), vs[buf] reads done
    };

    for (int tt = 0; tt < 64; tt += 2) {
        step(tt, kf1, kf0, P0, P1, 0);
        step(tt + 1, kf0, kf1, P1, P0, 1);
    }

    // ---- reduce l across the 4-lane query group (deferred) ----
    l += __shfl_xor(l, 16);
    l += __shfl_xor(l, 32);

    // ---- epilogue: out = gamma*(acc/l) + x ----
    float gm = gamma[0];
    float rl = 1.f / l;
    const float* xb = x + ((size_t)b * CC) * NN;
    float* ob = out + ((size_t)b * CC) * NN;
    int i = qb + li;
#pragma unroll
    for (int ct = 0; ct < 16; ++ct)
#pragma unroll
        for (int e = 0; e < 4; ++e) {
            int c = 16 * ct + 4 * g + e;
            size_t idx = (size_t)c * NN + i;
            ob[idx] = gm * (acc[ct][e] * rl) + xb[idx];
        }
}

// ---------------------------------------------------------------------------
extern "C" void kernel_launch(void* const* d_in, const int* in_sizes, int n_in,
                              void* d_out, int out_size, void* d_ws, size_t ws_size,
                              hipStream_t stream) {
    const float* x = (const float*)d_in[0];
    const float* Wq = (const float*)d_in[1];
    const float* bq = (const float*)d_in[2];
    const float* Wk = (const float*)d_in[3];
    const float* bk = (const float*)d_in[4];
    const float* Wv = (const float*)d_in[5];
    const float* bv = (const float*)d_in[6];
    const float* gamma = (const float*)d_in[7];
    float* out = (float*)d_out;

    // workspace layout (bytes):
    // q64 @0 (4MB) | k64 @4MB | vC @8MB (16MB) | Whi @24MB (160KB) |
    // Wlo @24MB+160KB | bcat @24MB+320KB
    unsigned short* ws16 = (unsigned short*)d_ws;
    unsigned short* q64w = ws16;
    unsigned short* k64w = ws16 + 2097152;
    unsigned short* vCw = ws16 + 4194304;
    unsigned short* Whiw = ws16 + 12582912;
    unsigned short* Wlow = Whiw + 81920;
    float* bcatw = (float*)(Wlow + 81920);

    prep_w_kernel<<<320, 256, 0, stream>>>(Wq, bq, Wk, bk, Wv, bv, Whiw, Wlow, bcatw);
    qkv_kernel<<<BB * (NN / 64), 256, 0, stream>>>(x, Whiw, Wlow, bcatw, q64w, k64w, vCw);
    attn_kernel<<<512, 256, 0, stream>>>(q64w, k64w, vCw, x, gamma, out);
}